// Round 7
// baseline (1314.859 us; speedup 1.0000x reference)
//
#include <hip/hip_runtime.h>
#include <math.h>

#define BATCH 4
#define NPTS  8192
#define KNN   16
#define KK    17               // top-17 incl. self (self key: d2 = +0 exactly)
#define NQ    (BATCH*NPTS)     // 32768
#define JMASK 0x1FFFu
#define EMASK 0xFFFFE000u      // top 19 bits of d2 (d2 >= +0 -> uint-sortable)
#define TOTAL_EDGES (BATCH*NPTS*KNN)

#define GC    32
#define GLO   (-4.5f)
#define GINV  (32.0f/9.0f)
#define NCELL (GC*GC*GC)       // 32768 Morton bins per batch

#define QPG   16               // queries per wave-group
#define WPB   4                // waves per block
#define NWAVES (NQ/QPG)        // 2048
#define GRIDQ (NWAVES/WPB)     // 512 blocks
#define SCAP  1536             // survivor cap per wave (u32 idx)
#define CAP2  36               // per-lane key-buffer rows
#define WIN   64               // tau0 index-window

__device__ __forceinline__ int cell_coord(float x) {
    int c = (int)floorf((x - GLO) * GINV);
    return min(GC - 1, max(0, c));
}
__device__ __forceinline__ unsigned spread5(unsigned v) {
    v &= 31u;
    v = (v | (v << 8)) & 0x100Fu;
    v = (v | (v << 4)) & 0x10C3u;
    v = (v | (v << 2)) & 0x1249u;
    return v;
}
__device__ __forceinline__ unsigned morton_id(float x, float y, float z) {
    return spread5((unsigned)cell_coord(x)) | (spread5((unsigned)cell_coord(y)) << 1)
         | (spread5((unsigned)cell_coord(z)) << 2);
}

// p = (-2xj,-2yj,-2zj,sqj); key packs truncated d2 + index (self -> d2 = +0 exact)
__device__ __forceinline__ unsigned mkkey(const float4 p, float xi, float yi,
                                          float zi, float sqi, unsigned j) {
    const float e  = fmaf(p.x, xi, fmaf(p.y, yi, p.z * zi)) + p.w;
    const float d2 = e + sqi;
    return (__float_as_uint(d2) & EMASK) | j;
}
__device__ __forceinline__ void ins17(unsigned (&a)[KK], unsigned key) {
    #pragma unroll
    for (int k = KK - 1; k >= 1; --k) a[k] = min(a[k], max(a[k - 1], key));
    a[0] = min(a[0], key);
}

// K1: Morton histogram; also zero loss accumulator + wave counter
__global__ void pel_hist(const float* __restrict__ pref, unsigned* __restrict__ hist,
                         float* __restrict__ acc, unsigned* __restrict__ bcnt) {
    const int idx = blockIdx.x * 256 + threadIdx.x;
    if (idx == 0) { acc[0] = 0.0f; bcnt[0] = 0u; }
    const int b = idx >> 13;
    const unsigned mid = morton_id(pref[3*idx], pref[3*idx+1], pref[3*idx+2]);
    atomicAdd(&hist[b * NCELL + mid], 1u);
}

// K2: per-batch exclusive scan of 32768 bins
__global__ __launch_bounds__(1024)
void pel_scan(const unsigned* __restrict__ hist, unsigned* __restrict__ off) {
    __shared__ unsigned s[1024];
    const unsigned* h = hist + blockIdx.x * NCELL;
    unsigned*       o = off  + blockIdx.x * NCELL;
    const int t = threadIdx.x;
    unsigned v[32], tot = 0;
    #pragma unroll
    for (int k = 0; k < 32; ++k) { v[k] = h[t * 32 + k]; tot += v[k]; }
    s[t] = tot;
    __syncthreads();
    for (int d = 1; d < 1024; d <<= 1) {
        const unsigned add = (t >= d) ? s[t - d] : 0u;
        __syncthreads();
        s[t] += add;
        __syncthreads();
    }
    unsigned run = s[t] - tot;
    #pragma unroll
    for (int k = 0; k < 32; ++k) { o[t * 32 + k] = run; run += v[k]; }
}

// K3: scatter to Morton-sorted order, packing (-2x,-2y,-2z,||x||^2) ref+pred
__global__ void pel_scatter(const float* __restrict__ pref, const float* __restrict__ pts,
                            unsigned* __restrict__ off,
                            float4* __restrict__ p4r, float4* __restrict__ p4p) {
    const int idx = blockIdx.x * 256 + threadIdx.x;
    const int b = idx >> 13;
    const float x = pref[3*idx], y = pref[3*idx+1], z = pref[3*idx+2];
    const unsigned mid = morton_id(x, y, z);
    const unsigned pos = atomicAdd(&off[b * NCELL + mid], 1u);
    p4r[b * NPTS + pos] = make_float4(-2.f*x, -2.f*y, -2.f*z, fmaf(x, x, fmaf(y, y, z*z)));
    const float px = pts[3*idx], py = pts[3*idx+1], pz = pts[3*idx+2];
    p4p[b * NPTS + pos] = make_float4(-2.f*px, -2.f*py, -2.f*pz,
                                      fmaf(px, px, fmaf(py, py, pz*pz)));
}

// K4: group-filter KNN + loss. 16 sorted queries per wave; wave-private LDS.
__global__ __launch_bounds__(256, 2)
void pel_query(const float4* __restrict__ P4r, const float4* __restrict__ P4p,
               float* __restrict__ acc_ws, unsigned* __restrict__ bcnt,
               float* __restrict__ out)
{
    __shared__ unsigned s_idx[WPB][SCAP];        // 24 KB
    __shared__ unsigned s_buf[WPB][CAP2][64];    // 36.9 KB
    __shared__ unsigned s_tauK[WPB][QPG];

    const int t    = threadIdx.x;
    const int w    = t >> 6, lane = t & 63;
    const int lq   = lane & (QPG - 1);           // query slot
    const int sp   = lane >> 4;                  // split 0..3
    const int g    = blockIdx.x * WPB + w;
    const int q    = g * QPG + lq;
    const int b    = q >> 13;
    const int i    = q & (NPTS - 1);             // sorted position in batch

    const float4* __restrict__ Pq = P4r + b * NPTS;
    const float4* __restrict__ Pp = P4p + b * NPTS;

    const float4 self = Pq[i];                   // (-2xi,-2yi,-2zi,sqi)
    const float xi = -0.5f * self.x, yi = -0.5f * self.y, zi = -0.5f * self.z;
    const float sqi = self.w;

    // ---- tau0: sound r17 bound from a 64-point sorted-index window ----
    unsigned a17[KK];
    #pragma unroll
    for (int k = 0; k < KK; ++k) a17[k] = 0xFFFFFFFFu;
    const int w0 = min(max(i - WIN/2, 0), NPTS - WIN);
    #pragma unroll 4
    for (int u = 0; u < WIN/4; ++u) {
        const int jw = w0 + sp * (WIN/4) + u;
        ins17(a17, mkkey(Pq[jw], xi, yi, zi, sqi, (unsigned)jw));
    }
    unsigned tp = 0;   // exact 17th of each sp-pair union (bitonic identity)
    #pragma unroll
    for (int k = 0; k < KK; ++k) {
        const unsigned bk = (unsigned)__shfl_xor((int)a17[KK-1-k], 16, 64);
        tp = max(tp, min(a17[k], bk));
    }
    const unsigned tau0 = min(tp, (unsigned)__shfl_xor((int)tp, 32, 64));

    // ---- group stats via shuffles (masks 1,2,4,8 mix the 16 queries) ----
    float mnx = xi, mxx = xi, mny = yi, mxy = yi, mnz = zi, mxz = zi;
    unsigned tmax = tau0;
    #pragma unroll
    for (int m = 1; m <= 8; m <<= 1) {
        mnx = fminf(mnx, __shfl_xor(mnx, m, 64)); mxx = fmaxf(mxx, __shfl_xor(mxx, m, 64));
        mny = fminf(mny, __shfl_xor(mny, m, 64)); mxy = fmaxf(mxy, __shfl_xor(mxy, m, 64));
        mnz = fminf(mnz, __shfl_xor(mnz, m, 64)); mxz = fmaxf(mxz, __shfl_xor(mxz, m, 64));
        tmax = max(tmax, (unsigned)__shfl_xor((int)tmax, m, 64));
    }
    const float cx = 0.5f * (mnx + mxx), cy = 0.5f * (mny + mxy), cz = 0.5f * (mnz + mxz);
    float dq = sqrtf((xi-cx)*(xi-cx) + (yi-cy)*(yi-cy) + (zi-cz)*(zi-cz));
    #pragma unroll
    for (int m = 1; m <= 8; m <<= 1) dq = fmaxf(dq, __shfl_xor(dq, m, 64));
    const float rt = sqrtf(__uint_as_float((tmax & EMASK) + 0x2000u));  // round-up
    const float R  = dq + rt + 2e-3f;
    const float sqc = cx*cx + cy*cy + cz*cz;
    const float thr = R * R - sqc;               // e(cand,center) <= thr

    // ---- shared coalesced scan: ballot-compact survivors into LDS ----
    int cnt = 0;
    bool ovf = false;
    for (int j0 = 0; j0 < NPTS && !ovf; j0 += 256) {
        float4 p[4];
        #pragma unroll
        for (int u = 0; u < 4; ++u) p[u] = Pq[j0 + u * 64 + lane];
        #pragma unroll
        for (int u = 0; u < 4; ++u) {
            const float e = fmaf(p[u].x, cx, fmaf(p[u].y, cy, fmaf(p[u].z, cz, p[u].w)));
            const bool acc = (e <= thr);
            const unsigned long long mask = __ballot(acc);
            const unsigned rank = __builtin_amdgcn_mbcnt_hi(
                (unsigned)(mask >> 32), __builtin_amdgcn_mbcnt_lo((unsigned)mask, 0u));
            if (acc) s_idx[w][cnt + rank] = (unsigned)(j0 + u * 64 + lane);
            cnt += (int)__popcll(mask);
        }
        if (cnt > SCAP - 256) ovf = true;        // sound fallback: full range
    }
    const int count = ovf ? NPTS : cnt;

    // ---- per-query selection: branchless push of keys <= tau0 ----
    unsigned tauL = tau0;
    int cnt2 = 0;
    int sbase = 0;
    const int steps = (count + 3) >> 2;
    for (; (sbase + 4) * 4 <= count; sbase += 4) {   // main: all lanes valid
        unsigned jj[4]; float4 pv[4];
        #pragma unroll
        for (int u = 0; u < 4; ++u) {
            const int n = (sbase + u) * 4 + sp;
            jj[u] = ovf ? (unsigned)n : s_idx[w][n];
        }
        #pragma unroll
        for (int u = 0; u < 4; ++u) pv[u] = Pq[jj[u]];
        #pragma unroll
        for (int u = 0; u < 4; ++u) {
            const unsigned key = mkkey(pv[u], xi, yi, zi, sqi, jj[u]);
            s_buf[w][cnt2][lane] = key;          // rejected rows overwritten
            cnt2 += (key <= tauL) ? 1 : 0;
            if (cnt2 == CAP2) {                  // rare exact compaction
                unsigned k17[KK];
                #pragma unroll
                for (int k = 0; k < KK; ++k) k17[k] = 0xFFFFFFFFu;
                for (int n2 = 0; n2 < cnt2; ++n2) ins17(k17, s_buf[w][n2][lane]);
                const unsigned th = k17[KK-1];
                int kept = 0;
                for (int n2 = 0; n2 < cnt2; ++n2) {
                    const unsigned c2 = s_buf[w][n2][lane];
                    if (c2 <= th) { s_buf[w][kept][lane] = c2; ++kept; }
                }
                cnt2 = kept; tauL = min(tauL, th);
            }
        }
    }
    for (; sbase < steps; ++sbase) {                 // tail with guards
        const int n = sbase * 4 + sp;
        if (n < count) {
            const unsigned jj = ovf ? (unsigned)n : s_idx[w][n];
            const unsigned key = mkkey(Pq[jj], xi, yi, zi, sqi, jj);
            s_buf[w][cnt2][lane] = key;
            cnt2 += (key <= tauL) ? 1 : 0;
            if (cnt2 == CAP2) {
                unsigned k17[KK];
                #pragma unroll
                for (int k = 0; k < KK; ++k) k17[k] = 0xFFFFFFFFu;
                for (int n2 = 0; n2 < cnt2; ++n2) ins17(k17, s_buf[w][n2][lane]);
                const unsigned th = k17[KK-1];
                int kept = 0;
                for (int n2 = 0; n2 < cnt2; ++n2) {
                    const unsigned c2 = s_buf[w][n2][lane];
                    if (c2 <= th) { s_buf[w][kept][lane] = c2; ++kept; }
                }
                cnt2 = kept; tauL = min(tauL, th);
            }
        }
    }

    // ---- per-lane sorted top-17, 4-run merge -> exact per-query tau ----
    unsigned c17[KK];
    #pragma unroll
    for (int k = 0; k < KK; ++k) c17[k] = 0xFFFFFFFFu;
    for (int n = 0; n < cnt2; ++n) ins17(c17, s_buf[w][n][lane]);
    #pragma unroll
    for (int k = 0; k < KK; ++k) s_buf[w][k][lane] = c17[k];   // runs: rows 0..16
    if (lane < 32) {
        const int mq = lane & (QPG - 1), half = lane >> 4;
        unsigned mm[KK];
        #pragma unroll
        for (int k = 0; k < KK; ++k) mm[k] = 0xFFFFFFFFu;
        for (int s2 = 2 * half; s2 < 2 * half + 2; ++s2) {
            const int col = mq + 16 * s2;
            for (int k = 0; k < KK; ++k) {
                const unsigned c = s_buf[w][k][col];
                if (c >= mm[KK-1]) break;
                ins17(mm, c);
            }
        }
        unsigned tau = 0;
        #pragma unroll
        for (int k = 0; k < KK; ++k) {
            const unsigned bk = (unsigned)__shfl_xor((int)mm[KK-1-k], 16, 64);
            tau = max(tau, min(mm[k], bk));
        }
        if (half == 0) s_tauK[w][mq] = tau;      // exact 17th key incl self
    }
    const unsigned tauK = s_tauK[w][lq];         // same-wave LDS: lockstep-safe

    // ---- loss over own accepted keys (each exactly once across 4 lanes) ----
    const float4 selfp = Pp[i];
    const float pxi = -0.5f * selfp.x, pyi = -0.5f * selfp.y, pzi = -0.5f * selfp.z;
    float accv = 0.0f;
    #pragma unroll
    for (int k = 0; k < KK; ++k) {
        if (c17[k] <= tauK) {
            const int j = (int)(c17[k] & JMASK);
            const float4 pr = Pq[j];
            const float er  = fmaf(pr.x, xi, fmaf(pr.y, yi, pr.z * zi)) + pr.w;
            const float d2r = fmaxf(er + sqi, 0.0f);
            const float4 pp = Pp[j];
            const float ep  = fmaf(pp.x, pxi, fmaf(pp.y, pyi, pp.z * pzi)) + pp.w;
            const float d2p = fmaxf(ep + selfp.w, 0.0f);
            accv += fabsf(sqrtf(d2r) - sqrtf(d2p));
        }
    }

    #pragma unroll
    for (int o = 32; o > 0; o >>= 1) accv += __shfl_down(accv, o, 64);
    if (lane == 0) {
        atomicAdd(acc_ws, accv);
        __threadfence();
        const unsigned old = atomicAdd(bcnt, 1u);
        if (old == NWAVES - 1) {
            __threadfence();
            const float total = atomicAdd(acc_ws, 0.0f);
            out[0] = total * (1.0f / (float)TOTAL_EDGES);
        }
    }
}

extern "C" void kernel_launch(void* const* d_in, const int* in_sizes, int n_in,
                              void* d_out, int out_size, void* d_ws, size_t ws_size,
                              hipStream_t stream) {
    const float* pref = (const float*)d_in[0];
    const float* pts  = (const float*)d_in[1];
    // ws: [P4r 512K (alias hist)][P4p 512K][off 512K][acc,bcnt]  = 1.57 MB
    float4*   P4r  = (float4*)d_ws;
    float4*   P4p  = P4r + NQ;
    unsigned* hist = (unsigned*)d_ws;                       // dead after scan
    unsigned* off  = (unsigned*)((char*)d_ws + 1048576);
    float*    acc  = (float*)((char*)d_ws + 1572864);
    unsigned* bcnt = (unsigned*)(acc + 1);
    float*    out  = (float*)d_out;

    hipMemsetAsync(hist, 0, BATCH * NCELL * sizeof(unsigned), stream);
    pel_hist   <<<NQ / 256, 256, 0, stream>>>(pref, hist, acc, bcnt);
    pel_scan   <<<BATCH, 1024, 0, stream>>>(hist, off);
    pel_scatter<<<NQ / 256, 256, 0, stream>>>(pref, pts, off, P4r, P4p);
    pel_query  <<<GRIDQ, 256, 0, stream>>>(P4r, P4p, acc, bcnt, out);
}

// Round 8
// 377.892 us; speedup vs baseline: 3.4795x; 3.4795x over previous
//
#include <hip/hip_runtime.h>
#include <math.h>

#define BATCH 4
#define NPTS  8192
#define KNN   16
#define KK    17               // top-17 incl. self (self key: d2 = +0 exactly)
#define NQ    (BATCH*NPTS)     // 32768
#define JMASK 0x1FFFu
#define EMASK 0xFFFFE000u      // top 19 bits of d2 (d2 >= +0 -> uint-sortable)
#define TOTAL_EDGES (BATCH*NPTS*KNN)

#define GC    32
#define GLO   (-4.5f)
#define GINV  (32.0f/9.0f)
#define NCELL (GC*GC*GC)

#define QPB   16               // queries per block (Morton-consecutive)
#define BLOCK 256              // 16 threads per query (sp = split 0..15)
#define GRIDQ (NQ/QPB)         // 2048 blocks
#define WIN   64               // tau0 window (sorted-index neighbors)
#define SEGCAP 512             // survivor segment per wave (u16)
#define CAP   21               // per-thread key-buffer rows (compact at 21 -> 17)

__device__ __forceinline__ int cell_coord(float x) {
    int c = (int)floorf((x - GLO) * GINV);
    return min(GC - 1, max(0, c));
}
__device__ __forceinline__ unsigned spread5(unsigned v) {
    v &= 31u;
    v = (v | (v << 8)) & 0x100Fu;
    v = (v | (v << 4)) & 0x10C3u;
    v = (v | (v << 2)) & 0x1249u;
    return v;
}
__device__ __forceinline__ unsigned morton_id(float x, float y, float z) {
    return spread5((unsigned)cell_coord(x)) | (spread5((unsigned)cell_coord(y)) << 1)
         | (spread5((unsigned)cell_coord(z)) << 2);
}
// p = (-2xj,-2yj,-2zj,sqj); key = truncated d2 | index (self -> d2 = +0 exact)
__device__ __forceinline__ unsigned mkkey(const float4 p, float xi, float yi,
                                          float zi, float sqi, unsigned j) {
    const float e  = fmaf(p.x, xi, fmaf(p.y, yi, p.z * zi)) + p.w;
    const float d2 = e + sqi;
    return (__float_as_uint(d2) & EMASK) | j;
}
__device__ __forceinline__ void ins17(unsigned (&a)[KK], unsigned key) {
    #pragma unroll
    for (int k = KK - 1; k >= 1; --k) a[k] = min(a[k], max(a[k - 1], key));
    a[0] = min(a[0], key);
}
__device__ __forceinline__ unsigned mbcnt64(unsigned long long m) {
    return __builtin_amdgcn_mbcnt_hi((unsigned)(m >> 32),
           __builtin_amdgcn_mbcnt_lo((unsigned)m, 0u));
}
// exact 17th of 16 sorted runs (RL entries, ~0u pad) at cols mq + s*16;
// lane pairs (t, t^16): halves merge 8 runs serially, bitonic-combine.
template<int RL>
__device__ __forceinline__ unsigned merge_tau(const unsigned (*s_key)[BLOCK], int t) {
    const int mq = t & (QPB - 1), half = (t >> 4) & 1;
    unsigned m[KK];
    #pragma unroll
    for (int k = 0; k < KK; ++k) m[k] = 0xFFFFFFFFu;
    for (int s = 8 * half; s < 8 * half + 8; ++s) {
        const int col = mq + s * QPB;
        for (int k = 0; k < RL; ++k) {
            const unsigned c = s_key[k][col];
            if (c >= m[KK - 1]) break;
            ins17(m, c);
        }
    }
    unsigned tau = 0;
    #pragma unroll
    for (int k = 0; k < KK; ++k) {
        const unsigned bk = (unsigned)__shfl_xor((int)m[KK - 1 - k], 16, 64);
        tau = max(tau, min(m[k], bk));
    }
    return tau;
}

// ---- build kernels (verified rounds 5/7, absmax 0.0) ----
__global__ void pel_hist(const float* __restrict__ pref, unsigned* __restrict__ hist,
                         float* __restrict__ acc, unsigned* __restrict__ bcnt) {
    const int idx = blockIdx.x * 256 + threadIdx.x;
    if (idx == 0) { acc[0] = 0.0f; bcnt[0] = 0u; }
    const int b = idx >> 13;
    const unsigned mid = morton_id(pref[3*idx], pref[3*idx+1], pref[3*idx+2]);
    atomicAdd(&hist[b * NCELL + mid], 1u);
}
__global__ __launch_bounds__(1024)
void pel_scan(const unsigned* __restrict__ hist, unsigned* __restrict__ off) {
    __shared__ unsigned s[1024];
    const unsigned* h = hist + blockIdx.x * NCELL;
    unsigned*       o = off  + blockIdx.x * NCELL;
    const int t = threadIdx.x;
    unsigned v[32], tot = 0;
    #pragma unroll
    for (int k = 0; k < 32; ++k) { v[k] = h[t * 32 + k]; tot += v[k]; }
    s[t] = tot;
    __syncthreads();
    for (int d = 1; d < 1024; d <<= 1) {
        const unsigned add = (t >= d) ? s[t - d] : 0u;
        __syncthreads();
        s[t] += add;
        __syncthreads();
    }
    unsigned run = s[t] - tot;
    #pragma unroll
    for (int k = 0; k < 32; ++k) { o[t * 32 + k] = run; run += v[k]; }
}
__global__ void pel_scatter(const float* __restrict__ pref, const float* __restrict__ pts,
                            unsigned* __restrict__ off,
                            float4* __restrict__ p4r, float4* __restrict__ p4p) {
    const int idx = blockIdx.x * 256 + threadIdx.x;
    const int b = idx >> 13;
    const float x = pref[3*idx], y = pref[3*idx+1], z = pref[3*idx+2];
    const unsigned mid = morton_id(x, y, z);
    const unsigned pos = atomicAdd(&off[b * NCELL + mid], 1u);
    p4r[b * NPTS + pos] = make_float4(-2.f*x, -2.f*y, -2.f*z, fmaf(x, x, fmaf(y, y, z*z)));
    const float px = pts[3*idx], py = pts[3*idx+1], pz = pts[3*idx+2];
    p4p[b * NPTS + pos] = make_float4(-2.f*px, -2.f*py, -2.f*pz,
                                      fmaf(px, px, fmaf(py, py, pz*pz)));
}

// ---- query kernel: group-filtered exact KNN + loss ----
__global__ __launch_bounds__(BLOCK, 6)
void pel_query(const float4* __restrict__ P4r, const float4* __restrict__ P4p,
               float* __restrict__ acc_ws, unsigned* __restrict__ bcnt,
               float* __restrict__ out)
{
    __shared__ unsigned s_key[CAP][BLOCK];          // 21 KB
    __shared__ unsigned short s_seg[4][SEGCAP];     // 4 KB
    __shared__ unsigned s_tau[QPB];
    __shared__ float s_grp[4];                      // thr, cx, cy, cz
    __shared__ int s_cnt[4], s_done[4];
    __shared__ float s_part[BLOCK / 64];

    const int t  = threadIdx.x;
    const int lq = t & (QPB - 1), sp = t >> 4;
    const int wv = t >> 6, lane = t & 63;
    const int q  = blockIdx.x * QPB + lq;
    const int b  = q >> 13;
    const int i  = q & (NPTS - 1);

    const float4* __restrict__ Pq = P4r + b * NPTS;
    const float4* __restrict__ Pp = P4p + b * NPTS;

    const float4 self = Pq[i];
    const float xi = -0.5f * self.x, yi = -0.5f * self.y, zi = -0.5f * self.z;
    const float sqi = self.w;

    // ---- Phase W: exact tau0 = 17th of 64-point Morton window ----
    unsigned al[4] = {~0u, ~0u, ~0u, ~0u};
    const int w0 = min(max(i - WIN / 2, 0), NPTS - WIN) + sp * 4;
    {
        float4 cw[4];
        #pragma unroll
        for (int u = 0; u < 4; ++u) cw[u] = Pq[w0 + u];
        #pragma unroll
        for (int u = 0; u < 4; ++u) {
            const unsigned key = mkkey(cw[u], xi, yi, zi, sqi, (unsigned)(w0 + u));
            #pragma unroll
            for (int k = 3; k >= 1; --k) al[k] = min(al[k], max(al[k - 1], key));
            al[0] = min(al[0], key);
        }
    }
    #pragma unroll
    for (int k = 0; k < 4; ++k) s_key[k][t] = al[k];
    __syncthreads();
    if (t < 32) {
        const unsigned tau0 = merge_tau<4>(s_key, t);
        if (t < QPB) s_tau[t] = tau0;
    }
    __syncthreads();

    // ---- Phase G: group ball (lanes 0-15 of wave 0) ----
    if (t < QPB) {
        const int i2 = (blockIdx.x * QPB + t) & (NPTS - 1);
        const float4 s2 = Pq[i2];
        const float qx = -0.5f * s2.x, qy = -0.5f * s2.y, qz = -0.5f * s2.z;
        float mnx = qx, mxx = qx, mny = qy, mxy = qy, mnz = qz, mxz = qz;
        #pragma unroll
        for (int m = 1; m <= 8; m <<= 1) {
            mnx = fminf(mnx, __shfl_xor(mnx, m, 64)); mxx = fmaxf(mxx, __shfl_xor(mxx, m, 64));
            mny = fminf(mny, __shfl_xor(mny, m, 64)); mxy = fmaxf(mxy, __shfl_xor(mxy, m, 64));
            mnz = fminf(mnz, __shfl_xor(mnz, m, 64)); mxz = fmaxf(mxz, __shfl_xor(mxz, m, 64));
        }
        const float cx = 0.5f * (mnx + mxx), cy = 0.5f * (mny + mxy), cz = 0.5f * (mnz + mxz);
        const float dq = sqrtf((qx-cx)*(qx-cx) + (qy-cy)*(qy-cy) + (qz-cz)*(qz-cz));
        const float rt = sqrtf(__uint_as_float((s_tau[t] & EMASK) + 0x2000u));
        float v = dq + rt;
        #pragma unroll
        for (int m = 1; m <= 8; m <<= 1) v = fmaxf(v, __shfl_xor(v, m, 64));
        if (t == 0) {
            const float R = v + 1e-3f;
            s_grp[0] = R * R - (cx*cx + cy*cy + cz*cz);   // e_c(j) <= thr
            s_grp[1] = cx; s_grp[2] = cy; s_grp[3] = cz;
        }
    }
    __syncthreads();
    const float thr = s_grp[0], gcx = s_grp[1], gcy = s_grp[2], gcz = s_grp[3];

    // ---- tiled cooperative scan + selection ----
    unsigned tauL = s_tau[lq];
    int cnt2 = 0;
    int kch = 0;                              // this wave's chunk ordinal 0..31
    for (;;) {
        __syncthreads();                      // prev tile's segments consumed
        int scnt = 0;
        while (kch < 32 && scnt <= SEGCAP - 64) {
            const int j = ((kch << 2) + wv) * 64 + lane;   // interleaved chunks
            const float4 p = Pq[j];
            const float e = fmaf(p.x, gcx, fmaf(p.y, gcy, fmaf(p.z, gcz, p.w)));
            const bool a = (e <= thr);
            const unsigned long long mk = __ballot(a);
            if (a) s_seg[wv][scnt + mbcnt64(mk)] = (unsigned short)j;
            scnt += (int)__popcll(mk);
            ++kch;
        }
        if (lane == 0) { s_cnt[wv] = scnt; s_done[wv] = (kch >= 32) ? 1 : 0; }
        __syncthreads();
        for (int w2 = 0; w2 < 4; ++w2) {      // selection: all 256 threads
            const int c = s_cnt[w2];
            int n = sp;
            unsigned jj0 = 0; float4 p0;
            if (n < c) { jj0 = s_seg[w2][n]; p0 = Pq[jj0]; }
            while (n < c) {
                const int n2 = n + QPB;
                unsigned jj1 = 0; float4 p1;
                if (n2 < c) { jj1 = s_seg[w2][n2]; p1 = Pq[jj1]; }  // prefetch
                const unsigned key = mkkey(p0, xi, yi, zi, sqi, jj0);
                s_key[cnt2][t] = key;                 // rejected rows overwritten
                cnt2 += (key <= tauL) ? 1 : 0;
                if (cnt2 == CAP) {                    // rare exact compaction
                    unsigned k17[KK];
                    #pragma unroll
                    for (int k = 0; k < KK; ++k) k17[k] = 0xFFFFFFFFu;
                    for (int n3 = 0; n3 < cnt2; ++n3) ins17(k17, s_key[n3][t]);
                    const unsigned th = k17[KK - 1];
                    int kept = 0;
                    for (int n3 = 0; n3 < cnt2; ++n3) {
                        const unsigned c2 = s_key[n3][t];
                        if (c2 <= th) { s_key[kept][t] = c2; ++kept; }
                    }
                    cnt2 = kept; tauL = min(tauL, th);
                }
                jj0 = jj1; p0 = p1; n = n2;
            }
        }
        if (s_done[0] && s_done[1] && s_done[2] && s_done[3]) break;
    }

    // ---- Phase C: per-thread sorted top-17 -> exact per-query tau ----
    unsigned c17[KK];
    #pragma unroll
    for (int k = 0; k < KK; ++k) c17[k] = 0xFFFFFFFFu;
    for (int n = 0; n < cnt2; ++n) ins17(c17, s_key[n][t]);
    __syncthreads();
    #pragma unroll
    for (int k = 0; k < KK; ++k) s_key[k][t] = c17[k];
    __syncthreads();
    if (t < 32) {
        const unsigned tauX = merge_tau<KK>(s_key, t);
        if (t < QPB) s_tau[t] = tauX;           // exact 17th key incl self
    }
    __syncthreads();
    const unsigned tauK = s_tau[lq];

    // ---- Phase D: full-precision |dr - dp| over accepted keys ----
    const float4 selfp = Pp[i];
    const float pxi = -0.5f * selfp.x, pyi = -0.5f * selfp.y, pzi = -0.5f * selfp.z;
    float accv = 0.0f;
    #pragma unroll
    for (int k = 0; k < KK; ++k) {
        if (c17[k] <= tauK) {
            const int j = (int)(c17[k] & JMASK);
            const float4 pr = Pq[j];
            const float er  = fmaf(pr.x, xi, fmaf(pr.y, yi, pr.z * zi)) + pr.w;
            const float d2r = fmaxf(er + sqi, 0.0f);
            const float4 pp = Pp[j];
            const float ep  = fmaf(pp.x, pxi, fmaf(pp.y, pyi, pp.z * pzi)) + pp.w;
            const float d2p = fmaxf(ep + selfp.w, 0.0f);
            accv += fabsf(sqrtf(d2r) - sqrtf(d2p));
        }
    }

    #pragma unroll
    for (int o = 32; o > 0; o >>= 1) accv += __shfl_down(accv, o, 64);
    if (lane == 0) s_part[wv] = accv;
    __syncthreads();
    if (t == 0) {
        float s = 0.0f;
        #pragma unroll
        for (int w2 = 0; w2 < BLOCK / 64; ++w2) s += s_part[w2];
        atomicAdd(acc_ws, s);
        __threadfence();
        const unsigned old = atomicAdd(bcnt, 1u);
        if (old == GRIDQ - 1) {
            __threadfence();
            const float total = atomicAdd(acc_ws, 0.0f);
            out[0] = total * (1.0f / (float)TOTAL_EDGES);
        }
    }
}

extern "C" void kernel_launch(void* const* d_in, const int* in_sizes, int n_in,
                              void* d_out, int out_size, void* d_ws, size_t ws_size,
                              hipStream_t stream) {
    const float* pref = (const float*)d_in[0];
    const float* pts  = (const float*)d_in[1];
    // ws: [P4r 512K (alias hist)][P4p 512K][off 512K][acc,bcnt]
    float4*   P4r  = (float4*)d_ws;
    float4*   P4p  = P4r + NQ;
    unsigned* hist = (unsigned*)d_ws;                      // dead after scan
    unsigned* off  = (unsigned*)((char*)d_ws + 1048576);
    float*    acc  = (float*)((char*)d_ws + 1572864);
    unsigned* bcnt = (unsigned*)(acc + 1);
    float*    out  = (float*)d_out;

    hipMemsetAsync(hist, 0, BATCH * NCELL * sizeof(unsigned), stream);
    pel_hist   <<<NQ / 256, 256, 0, stream>>>(pref, hist, acc, bcnt);
    pel_scan   <<<BATCH, 1024, 0, stream>>>(hist, off);
    pel_scatter<<<NQ / 256, 256, 0, stream>>>(pref, pts, off, P4r, P4p);
    pel_query  <<<GRIDQ, BLOCK, 0, stream>>>(P4r, P4p, acc, bcnt, out);
}

// Round 9
// 254.935 us; speedup vs baseline: 5.1576x; 1.4823x over previous
//
#include <hip/hip_runtime.h>
#include <math.h>

#define BATCH 4
#define NPTS  8192
#define KNN   16
#define KK    17               // top-17 incl. self (self key: d2 = +0 exactly)
#define NQ    (BATCH*NPTS)     // 32768
#define JMASK 0x1FFFu
#define EMASK 0xFFFFE000u      // top 19 bits of d2 (d2 >= +0 -> uint-sortable)
#define TOTAL_EDGES (BATCH*NPTS*KNN)

#define GC    32
#define GLO   (-4.5f)
#define GINV  (32.0f/9.0f)
#define NCELL (GC*GC*GC)

#define NG    128              // candidate groups per batch (64 pts each)
#define GSZ   64

#define QPB   16               // queries per block (Morton-consecutive)
#define BLOCK 256              // 16 threads per query (sp = 0..15)
#define GRIDQ (NQ/QPB)         // 2048 blocks
#define WIN   64               // tau0 window (sorted-index neighbors)
#define CAP   21               // key-buffer rows (compact when cnt > 17)

__device__ __forceinline__ int cell_coord(float x) {
    int c = (int)floorf((x - GLO) * GINV);
    return min(GC - 1, max(0, c));
}
__device__ __forceinline__ unsigned spread5(unsigned v) {
    v &= 31u;
    v = (v | (v << 8)) & 0x100Fu;
    v = (v | (v << 4)) & 0x10C3u;
    v = (v | (v << 2)) & 0x1249u;
    return v;
}
__device__ __forceinline__ unsigned morton_id(float x, float y, float z) {
    return spread5((unsigned)cell_coord(x)) | (spread5((unsigned)cell_coord(y)) << 1)
         | (spread5((unsigned)cell_coord(z)) << 2);
}
// p = (-2xj,-2yj,-2zj,sqj); key = truncated d2 | index (self -> d2 = +0 exact)
__device__ __forceinline__ unsigned mkkey(const float4 p, float xi, float yi,
                                          float zi, float sqi, unsigned j) {
    const float e  = fmaf(p.x, xi, fmaf(p.y, yi, p.z * zi)) + p.w;
    const float d2 = e + sqi;
    return (__float_as_uint(d2) & EMASK) | j;
}
__device__ __forceinline__ void ins17(unsigned (&a)[KK], unsigned key) {
    #pragma unroll
    for (int k = KK - 1; k >= 1; --k) a[k] = min(a[k], max(a[k - 1], key));
    a[0] = min(a[0], key);
}
// exact 17th of 16 sorted runs (RL entries, ~0u pad) at cols mq + s*16
template<int RL>
__device__ __forceinline__ unsigned merge_tau(const unsigned (*s_key)[BLOCK], int t) {
    const int mq = t & (QPB - 1), half = (t >> 4) & 1;
    unsigned m[KK];
    #pragma unroll
    for (int k = 0; k < KK; ++k) m[k] = 0xFFFFFFFFu;
    for (int s = 8 * half; s < 8 * half + 8; ++s) {
        const int col = mq + s * QPB;
        for (int k = 0; k < RL; ++k) {
            const unsigned c = s_key[k][col];
            if (c >= m[KK - 1]) break;
            ins17(m, c);
        }
    }
    unsigned tau = 0;
    #pragma unroll
    for (int k = 0; k < KK; ++k) {
        const unsigned bk = (unsigned)__shfl_xor((int)m[KK - 1 - k], 16, 64);
        tau = max(tau, min(m[k], bk));
    }
    return tau;
}

// ---- build kernels (verified rounds 5/7/8, absmax 0.0) ----
__global__ void pel_hist(const float* __restrict__ pref, unsigned* __restrict__ hist,
                         float* __restrict__ acc, unsigned* __restrict__ bcnt) {
    const int idx = blockIdx.x * 256 + threadIdx.x;
    if (idx == 0) { acc[0] = 0.0f; bcnt[0] = 0u; }
    const int b = idx >> 13;
    const unsigned mid = morton_id(pref[3*idx], pref[3*idx+1], pref[3*idx+2]);
    atomicAdd(&hist[b * NCELL + mid], 1u);
}
__global__ __launch_bounds__(1024)
void pel_scan(const unsigned* __restrict__ hist, unsigned* __restrict__ off) {
    __shared__ unsigned s[1024];
    const unsigned* h = hist + blockIdx.x * NCELL;
    unsigned*       o = off  + blockIdx.x * NCELL;
    const int t = threadIdx.x;
    unsigned v[32], tot = 0;
    #pragma unroll
    for (int k = 0; k < 32; ++k) { v[k] = h[t * 32 + k]; tot += v[k]; }
    s[t] = tot;
    __syncthreads();
    for (int d = 1; d < 1024; d <<= 1) {
        const unsigned add = (t >= d) ? s[t - d] : 0u;
        __syncthreads();
        s[t] += add;
        __syncthreads();
    }
    unsigned run = s[t] - tot;
    #pragma unroll
    for (int k = 0; k < 32; ++k) { o[t * 32 + k] = run; run += v[k]; }
}
__global__ void pel_scatter(const float* __restrict__ pref, const float* __restrict__ pts,
                            unsigned* __restrict__ off,
                            float4* __restrict__ p4r, float4* __restrict__ p4p) {
    const int idx = blockIdx.x * 256 + threadIdx.x;
    const int b = idx >> 13;
    const float x = pref[3*idx], y = pref[3*idx+1], z = pref[3*idx+2];
    const unsigned mid = morton_id(x, y, z);
    const unsigned pos = atomicAdd(&off[b * NCELL + mid], 1u);
    p4r[b * NPTS + pos] = make_float4(-2.f*x, -2.f*y, -2.f*z, fmaf(x, x, fmaf(y, y, z*z)));
    const float px = pts[3*idx], py = pts[3*idx+1], pz = pts[3*idx+2];
    p4p[b * NPTS + pos] = make_float4(-2.f*px, -2.f*py, -2.f*pz,
                                      fmaf(px, px, fmaf(py, py, pz*pz)));
}
// group bounding balls: one wave per 64-point group -> (cx,cy,cz,r)
__global__ __launch_bounds__(256)
void pel_gstat(const float4* __restrict__ P4r, float4* __restrict__ gball) {
    const int wv = threadIdx.x >> 6, lane = threadIdx.x & 63;
    const int gid = blockIdx.x * 4 + wv;             // 0 .. BATCH*NG-1
    const int b = gid >> 7, g = gid & (NG - 1);
    const float4 p = P4r[b * NPTS + g * GSZ + lane];
    const float x = -0.5f * p.x, y = -0.5f * p.y, z = -0.5f * p.z;
    float mnx = x, mxx = x, mny = y, mxy = y, mnz = z, mxz = z;
    #pragma unroll
    for (int m = 1; m <= 32; m <<= 1) {
        mnx = fminf(mnx, __shfl_xor(mnx, m, 64)); mxx = fmaxf(mxx, __shfl_xor(mxx, m, 64));
        mny = fminf(mny, __shfl_xor(mny, m, 64)); mxy = fmaxf(mxy, __shfl_xor(mxy, m, 64));
        mnz = fminf(mnz, __shfl_xor(mnz, m, 64)); mxz = fmaxf(mxz, __shfl_xor(mxz, m, 64));
    }
    const float cx = 0.5f * (mnx + mxx), cy = 0.5f * (mny + mxy), cz = 0.5f * (mnz + mxz);
    float d = sqrtf((x-cx)*(x-cx) + (y-cy)*(y-cy) + (z-cz)*(z-cz));
    #pragma unroll
    for (int m = 1; m <= 32; m <<= 1) d = fmaxf(d, __shfl_xor(d, m, 64));
    if (lane == 0) gball[gid] = make_float4(cx, cy, cz, d);
}

// ---- query kernel: group-granular filter + round-6 branchless selection ----
__global__ __launch_bounds__(BLOCK, 8)
void pel_query(const float4* __restrict__ P4r, const float4* __restrict__ P4p,
               const float4* __restrict__ gball,
               float* __restrict__ acc_ws, unsigned* __restrict__ bcnt,
               float* __restrict__ out)
{
    __shared__ unsigned s_key[CAP][BLOCK];        // 21 KB
    __shared__ unsigned s_tau[QPB];
    __shared__ unsigned short s_glist[NG];
    __shared__ float s_grp[4];                    // qcx, qcy, qcz, Rq
    __shared__ int s_ng;
    __shared__ float s_part[BLOCK / 64];

    const int t  = threadIdx.x;
    const int lq = t & (QPB - 1), sp = t >> 4;
    const int q  = blockIdx.x * QPB + lq;
    const int b  = q >> 13;
    const int i  = q & (NPTS - 1);

    const float4* __restrict__ Pq = P4r + b * NPTS;
    const float4* __restrict__ Pp = P4p + b * NPTS;
    const float4* __restrict__ Gb = gball + b * NG;

    const float4 self = Pq[i];
    const float xi = -0.5f * self.x, yi = -0.5f * self.y, zi = -0.5f * self.z;
    const float sqi = self.w;

    // ---- Phase W: exact tau0 = 17th of 64-point Morton window ----
    unsigned al[4] = {~0u, ~0u, ~0u, ~0u};
    const int w0 = min(max(i - WIN / 2, 0), NPTS - WIN) + sp * 4;
    {
        float4 cw[4];
        #pragma unroll
        for (int u = 0; u < 4; ++u) cw[u] = Pq[w0 + u];
        #pragma unroll
        for (int u = 0; u < 4; ++u) {
            const unsigned key = mkkey(cw[u], xi, yi, zi, sqi, (unsigned)(w0 + u));
            #pragma unroll
            for (int k = 3; k >= 1; --k) al[k] = min(al[k], max(al[k - 1], key));
            al[0] = min(al[0], key);
        }
    }
    #pragma unroll
    for (int k = 0; k < 4; ++k) s_key[k][t] = al[k];
    __syncthreads();
    if (t < 32) {
        const unsigned tau0 = merge_tau<4>(s_key, t);
        if (t < QPB) s_tau[t] = tau0;
    }
    __syncthreads();

    // ---- Phase G: query-group ball (lanes 0-15) ----
    if (t < QPB) {
        if (t == 0) s_ng = 0;
        const int i2 = (blockIdx.x * QPB + t) & (NPTS - 1);
        const float4 s2 = Pq[i2];
        const float qx = -0.5f * s2.x, qy = -0.5f * s2.y, qz = -0.5f * s2.z;
        float mnx = qx, mxx = qx, mny = qy, mxy = qy, mnz = qz, mxz = qz;
        #pragma unroll
        for (int m = 1; m <= 8; m <<= 1) {
            mnx = fminf(mnx, __shfl_xor(mnx, m, 64)); mxx = fmaxf(mxx, __shfl_xor(mxx, m, 64));
            mny = fminf(mny, __shfl_xor(mny, m, 64)); mxy = fmaxf(mxy, __shfl_xor(mxy, m, 64));
            mnz = fminf(mnz, __shfl_xor(mnz, m, 64)); mxz = fmaxf(mxz, __shfl_xor(mxz, m, 64));
        }
        const float cx = 0.5f * (mnx + mxx), cy = 0.5f * (mny + mxy), cz = 0.5f * (mnz + mxz);
        const float dq = sqrtf((qx-cx)*(qx-cx) + (qy-cy)*(qy-cy) + (qz-cz)*(qz-cz));
        const float rt = sqrtf(__uint_as_float((s_tau[t] & EMASK) + 0x2000u));
        float v = dq + rt;
        #pragma unroll
        for (int m = 1; m <= 8; m <<= 1) v = fmaxf(v, __shfl_xor(v, m, 64));
        if (t == 0) {
            s_grp[0] = cx; s_grp[1] = cy; s_grp[2] = cz; s_grp[3] = v + 1e-3f;
        }
    }
    __syncthreads();

    // ---- Phase F: test 128 candidate-group balls, compact accepted IDs ----
    if (t < NG) {
        const float4 gb = Gb[t];
        const float dx = gb.x - s_grp[0], dy = gb.y - s_grp[1], dz = gb.z - s_grp[2];
        const float rhs = s_grp[3] + gb.w;
        if (dx*dx + dy*dy + dz*dz <= rhs * rhs) {
            const int slot = atomicAdd(&s_ng, 1);
            s_glist[slot] = (unsigned short)t;
        }
    }
    __syncthreads();
    const int ng = s_ng;

    // ---- Phase B: branchless push over accepted groups (contiguous loads) ----
    unsigned tauL = s_tau[lq];
    int cnt = 0;
    for (int gi = 0; gi < ng; ++gi) {
        const int gb4 = (int)s_glist[gi] * GSZ + sp * 4;
        float4 c[4];
        #pragma unroll
        for (int u = 0; u < 4; ++u) c[u] = Pq[gb4 + u];
        #pragma unroll
        for (int u = 0; u < 4; ++u) {
            const unsigned key = mkkey(c[u], xi, yi, zi, sqi, (unsigned)(gb4 + u));
            s_key[cnt][t] = key;                  // rejected rows overwritten
            cnt += (key <= tauL) ? 1 : 0;
        }
        if (cnt > CAP - 4) {                      // rare exact compaction
            unsigned k17[KK];
            #pragma unroll
            for (int k = 0; k < KK; ++k) k17[k] = 0xFFFFFFFFu;
            for (int n = 0; n < cnt; ++n) ins17(k17, s_key[n][t]);
            const unsigned th = k17[KK - 1];
            int kept = 0;
            for (int n = 0; n < cnt; ++n) {
                const unsigned c2 = s_key[n][t];
                if (c2 <= th) { s_key[kept][t] = c2; ++kept; }
            }
            cnt = kept; tauL = min(tauL, th);
        }
    }

    // ---- Phase C: per-thread sorted top-17 -> exact per-query tau ----
    unsigned c17[KK];
    #pragma unroll
    for (int k = 0; k < KK; ++k) c17[k] = 0xFFFFFFFFu;
    for (int n = 0; n < cnt; ++n) ins17(c17, s_key[n][t]);
    __syncthreads();
    #pragma unroll
    for (int k = 0; k < KK; ++k) s_key[k][t] = c17[k];
    __syncthreads();
    if (t < 32) {
        const unsigned tauX = merge_tau<KK>(s_key, t);
        if (t < QPB) s_tau[t] = tauX;             // exact 17th key incl self
    }
    __syncthreads();
    const unsigned tauK = s_tau[lq];

    // ---- Phase D: full-precision |dr - dp| over accepted keys ----
    const float4 selfp = Pp[i];
    const float pxi = -0.5f * selfp.x, pyi = -0.5f * selfp.y, pzi = -0.5f * selfp.z;
    float accv = 0.0f;
    #pragma unroll
    for (int k = 0; k < KK; ++k) {
        if (c17[k] <= tauK) {
            const int j = (int)(c17[k] & JMASK);
            const float4 pr = Pq[j];
            const float er  = fmaf(pr.x, xi, fmaf(pr.y, yi, pr.z * zi)) + pr.w;
            const float d2r = fmaxf(er + sqi, 0.0f);
            const float4 pp = Pp[j];
            const float ep  = fmaf(pp.x, pxi, fmaf(pp.y, pyi, pp.z * pzi)) + pp.w;
            const float d2p = fmaxf(ep + selfp.w, 0.0f);
            accv += fabsf(sqrtf(d2r) - sqrtf(d2p));
        }
    }

    #pragma unroll
    for (int o = 32; o > 0; o >>= 1) accv += __shfl_down(accv, o, 64);
    if ((t & 63) == 0) s_part[t >> 6] = accv;
    __syncthreads();
    if (t == 0) {
        float s = 0.0f;
        #pragma unroll
        for (int w2 = 0; w2 < BLOCK / 64; ++w2) s += s_part[w2];
        atomicAdd(acc_ws, s);
        __threadfence();
        const unsigned old = atomicAdd(bcnt, 1u);
        if (old == GRIDQ - 1) {
            __threadfence();
            const float total = atomicAdd(acc_ws, 0.0f);
            out[0] = total * (1.0f / (float)TOTAL_EDGES);
        }
    }
}

extern "C" void kernel_launch(void* const* d_in, const int* in_sizes, int n_in,
                              void* d_out, int out_size, void* d_ws, size_t ws_size,
                              hipStream_t stream) {
    const float* pref = (const float*)d_in[0];
    const float* pts  = (const float*)d_in[1];
    // ws: [P4r 512K (alias hist)][P4p 512K][off 512K][gball 8K][acc,bcnt]
    float4*   P4r  = (float4*)d_ws;
    float4*   P4p  = P4r + NQ;
    unsigned* hist = (unsigned*)d_ws;                      // dead after scan
    unsigned* off  = (unsigned*)((char*)d_ws + 1048576);
    float4*   gball= (float4*)((char*)d_ws + 1572864);
    float*    acc  = (float*)((char*)d_ws + 1581056);
    unsigned* bcnt = (unsigned*)(acc + 1);
    float*    out  = (float*)d_out;

    hipMemsetAsync(hist, 0, BATCH * NCELL * sizeof(unsigned), stream);
    pel_hist   <<<NQ / 256, 256, 0, stream>>>(pref, hist, acc, bcnt);
    pel_scan   <<<BATCH, 1024, 0, stream>>>(hist, off);
    pel_scatter<<<NQ / 256, 256, 0, stream>>>(pref, pts, off, P4r, P4p);
    pel_gstat  <<<(BATCH * NG) / 4, 256, 0, stream>>>(P4r, gball);
    pel_query  <<<GRIDQ, BLOCK, 0, stream>>>(P4r, P4p, gball, acc, bcnt, out);
}